// Round 9
// baseline (478.652 us; speedup 1.0000x reference)
//
#include <hip/hip_runtime.h>

// HMM scaled forward — single fused kernel, emission via MFMA on raw one-hot.
//   BATCH=128, T=8192, N_STATES=128, EMIT=64
// No decode pass: E^T = (64*B)^T @ x_t^T computed by 16 mfma/step directly on
// the fp32 one-hot rows (bf16 cast = take top 16 bits: 0.0/1.0 exact; one
// nonzero term per column -> E bit-identical to a B-table gather).
// R^T = A^T @ alpha^T (32 mfma/step, permuted-K so packed D == next B-frag;
// alpha never leaves registers). Telescoped normalization (2-3 shfl
// reductions per chunk). One wave per (batch-group of 16, chunk of 32 + 8
// warmup). 256 MiB is streamed exactly once, overlapped with compute.

#define BATCH 128
#define TLEN 8192
#define NS 128
#define EMIT 64
#define NCHUNK 256
#define CLEN (TLEN / NCHUNK)   // 32
#define WARM 8
#define BG 8                   // batch groups of 16
#define LN64 4.158883083359672f

typedef __attribute__((ext_vector_type(8))) short short8;
typedef __attribute__((ext_vector_type(4))) float floatx4;
typedef __attribute__((ext_vector_type(4))) unsigned int uintx4;

__device__ __forceinline__ unsigned f2bf(float f) {
    return (__float_as_uint(f) + 0x8000u) >> 16;   // round-half-up to bf16
}

__global__ void zero_ll(float* __restrict__ out_ll) {
    out_ll[threadIdx.x] = 0.f;
}

__global__ __launch_bounds__(64, 2) void hmm_scan(
        const float* __restrict__ x,      // one-hot [B][T][EMIT] fp32
        const float* __restrict__ Amat,
        const float* __restrict__ Bmat,
        const float* __restrict__ Ivec,
        float* __restrict__ out_alpha,    // [BATCH][NS]
        float* __restrict__ out_ll)       // [BATCH]
{
    const int lane = threadIdx.x;
    const int n = lane & 15;              // batch within group (D col / B-op col)
    const int q = lane >> 4;              // quad
    const int bg = blockIdx.x >> 8;       // / NCHUNK
    const int c = blockIdx.x & (NCHUNK - 1);
    const bool first = (c == 0);
    const bool lastc = (c == NCHUNK - 1);
    const int steps = first ? CLEN : (CLEN + WARM);
    const int t0 = first ? 0 : c * CLEN - WARM;

    // A fragments with permuted K-order so packed D == next B-frag.
    // position u = 32kf+8q+j -> state 32(u>>5)+16((u>>2)&1)+4((u>>3)&3)+(u&3)
    short8 af[8][4];
    #pragma unroll
    for (int mt = 0; mt < 8; ++mt)
        #pragma unroll
        for (int kf = 0; kf < 4; ++kf) {
            short8 v;
            #pragma unroll
            for (int j = 0; j < 8; ++j) {
                int u = 32 * kf + 8 * q + j;
                int sk = 32 * (u >> 5) + 16 * ((u >> 2) & 1)
                       + 4 * ((u >> 3) & 3) + (u & 3);
                v[j] = (short)f2bf(Amat[sk * NS + 16 * mt + n]);
            }
            af[mt][kf] = v;
        }

    // (64*B)^T fragments as A-operand of the E-mfma: identity K-map.
    // bfB[mt][kf2][j] = bf16(64*B[32kf2+8q+j][16mt+n])
    short8 bfB[8][2];
    #pragma unroll
    for (int mt = 0; mt < 8; ++mt)
        #pragma unroll
        for (int kf = 0; kf < 2; ++kf) {
            short8 v;
            #pragma unroll
            for (int j = 0; j < 8; ++j)
                v[j] = (short)f2bf(64.0f * Bmat[(32 * kf + 8 * q + j) * NS + 16 * mt + n]);
            bfB[mt][kf] = v;
        }

    // I broadcast (first chunk only): I[16mt+4q+r]
    floatx4 iv[8];
    if (first) {
        #pragma unroll
        for (int mt = 0; mt < 8; ++mt)
            iv[mt] = *(const floatx4*)(Ivec + 16 * mt + 4 * q);
    }

    // this lane's one-hot row base (batch bg*16+n), as float4s
    const floatx4* xrow = (const floatx4*)x + (size_t)(bg * 16 + n) * (TLEN * 16);

    // loop-carried packed alpha (bf16 pairs); init uniform for warmup
    unsigned pk[16];
    #pragma unroll
    for (int i = 0; i < 16; ++i) pk[i] = 0x3C003C00u;   // bf16(1/128) x2

    float s_pre = 1.0f, s_penult = 1.0f, s_end = 1.0f;

    for (int it = 0; it < steps; ++it) {
        // load this step's 16 one-hot floats (emits 32kf+8q+j) and cast bf16
        const floatx4* p = xrow + ((t0 + it) * 16 + 2 * q);
        floatx4 x0 = p[0], x1 = p[1], x2 = p[8], x3 = p[9];
        unsigned xw[4];
        xw[0] = __builtin_amdgcn_perm(__float_as_uint(x0.y), __float_as_uint(x0.x), 0x07060302u);
        xw[1] = __builtin_amdgcn_perm(__float_as_uint(x0.w), __float_as_uint(x0.z), 0x07060302u);
        xw[2] = __builtin_amdgcn_perm(__float_as_uint(x1.y), __float_as_uint(x1.x), 0x07060302u);
        xw[3] = __builtin_amdgcn_perm(__float_as_uint(x1.w), __float_as_uint(x1.z), 0x07060302u);
        uintx4 xu0 = {xw[0], xw[1], xw[2], xw[3]};
        xw[0] = __builtin_amdgcn_perm(__float_as_uint(x2.y), __float_as_uint(x2.x), 0x07060302u);
        xw[1] = __builtin_amdgcn_perm(__float_as_uint(x2.w), __float_as_uint(x2.z), 0x07060302u);
        xw[2] = __builtin_amdgcn_perm(__float_as_uint(x3.y), __float_as_uint(x3.x), 0x07060302u);
        xw[3] = __builtin_amdgcn_perm(__float_as_uint(x3.w), __float_as_uint(x3.z), 0x07060302u);
        uintx4 xu1 = {xw[0], xw[1], xw[2], xw[3]};
        short8 xf0 = __builtin_bit_cast(short8, xu0);
        short8 xf1 = __builtin_bit_cast(short8, xu1);

        // previous alpha as B-fragments
        short8 bfa[4];
        #pragma unroll
        for (int kf = 0; kf < 4; ++kf) {
            uintx4 u4 = {pk[4 * kf], pk[4 * kf + 1], pk[4 * kf + 2], pk[4 * kf + 3]};
            bfa[kf] = __builtin_bit_cast(short8, u4);
        }

        const bool init0 = first && (it == 0);
        floatx4 acc[8];
        #pragma unroll
        for (int mt = 0; mt < 8; ++mt) {
            // E^T tile: 2 mfma over K=64 (one-hot -> exact row of 64*B)
            floatx4 e = {0.f, 0.f, 0.f, 0.f};
            e = __builtin_amdgcn_mfma_f32_16x16x32_bf16(bfB[mt][0], xf0, e, 0, 0, 0);
            e = __builtin_amdgcn_mfma_f32_16x16x32_bf16(bfB[mt][1], xf1, e, 0, 0, 0);
            if (init0) {
                // alpha0 = E0 * I
                acc[mt].x = e.x * iv[mt].x; acc[mt].y = e.y * iv[mt].y;
                acc[mt].z = e.z * iv[mt].z; acc[mt].w = e.w * iv[mt].w;
            } else {
                // R^T tile: 4 mfma over K=128 (permuted)
                floatx4 r = {0.f, 0.f, 0.f, 0.f};
                #pragma unroll
                for (int kf = 0; kf < 4; ++kf)
                    r = __builtin_amdgcn_mfma_f32_16x16x32_bf16(af[mt][kf], bfa[kf], r, 0, 0, 0);
                acc[mt].x = e.x * r.x; acc[mt].y = e.y * r.y;
                acc[mt].z = e.z * r.z; acc[mt].w = e.w * r.w;
            }
        }

        // rare per-chunk reductions (wave-uniform branch)
        bool need_red = (it == steps - 1) || (!first && it == WARM - 1) ||
                        (lastc && it == steps - 2);
        if (need_red) {
            float zz = 0.f;
            #pragma unroll
            for (int mt = 0; mt < 8; ++mt)
                zz += (acc[mt].x + acc[mt].y) + (acc[mt].z + acc[mt].w);
            zz += __shfl_xor(zz, 16, 64);
            zz += __shfl_xor(zz, 32, 64);      // S-bar per batch, all q-lanes
            if (it == steps - 1) s_end = zz;
            else if (lastc && it == steps - 2) s_penult = zz;
            else s_pre = zz;
        }

        if (lastc && it == steps - 1) {
            // alpha_f = alpha-bar_{T-1} / (64 * S-bar_{T-2})
            float inv = 1.0f / (64.0f * s_penult);
            #pragma unroll
            for (int mt = 0; mt < 8; ++mt) {
                floatx4 o4;
                o4.x = acc[mt].x * inv; o4.y = acc[mt].y * inv;
                o4.z = acc[mt].z * inv; o4.w = acc[mt].w * inv;
                *(floatx4*)(out_alpha + (bg * 16 + n) * NS + 16 * mt + 4 * q) = o4;
            }
        }

        // pack to bf16 pairs: directly forms next step's B-fragments
        #pragma unroll
        for (int mt = 0; mt < 8; ++mt) {
            unsigned u0 = __float_as_uint(acc[mt].x) + 0x8000u;
            unsigned u1 = __float_as_uint(acc[mt].y) + 0x8000u;
            unsigned u2 = __float_as_uint(acc[mt].z) + 0x8000u;
            unsigned u3 = __float_as_uint(acc[mt].w) + 0x8000u;
            pk[2 * mt]     = __builtin_amdgcn_perm(u1, u0, 0x07060302u);
            pk[2 * mt + 1] = __builtin_amdgcn_perm(u3, u2, 0x07060302u);
        }
    }

    // chunk ll partial: telescoped  log(S_end) - log(S_pre) - CLEN*ln(64)
    if (q == 0) {
        float ll = __logf(s_end) - __logf(s_pre) - (float)CLEN * LN64;
        atomicAdd(&out_ll[bg * 16 + n], ll);
    }
}

extern "C" void kernel_launch(void* const* d_in, const int* in_sizes, int n_in,
                              void* d_out, int out_size, void* d_ws, size_t ws_size,
                              hipStream_t stream) {
    const float* x = (const float*)d_in[0];   // [B, T, EMIT] one-hot fp32
    const float* I = (const float*)d_in[1];   // [NS]
    const float* A = (const float*)d_in[2];   // [NS, NS]
    const float* B = (const float*)d_in[3];   // [EMIT, NS]
    float* out = (float*)d_out;               // alpha_f [B*NS] ++ loglik [B]

    zero_ll<<<1, BATCH, 0, stream>>>(out + BATCH * NS);
    hmm_scan<<<BG * NCHUNK, 64, 0, stream>>>(
        x, A, B, I, out, out + BATCH * NS);
}

// Round 10
// 412.191 us; speedup vs baseline: 1.1612x; 1.1612x over previous
//
#include <hip/hip_runtime.h>

// HMM scaled forward — streaming decode + register-resident MFMA scan (r5
// structure; decode re-tuned: plain loads, 4-deep MLP, grid-stride).
//   BATCH=128, T=8192, N_STATES=128, EMIT=64
// decode_onehot: 256 MiB one-hot -> obsG[bg][n][t] bytes (1 MiB), HBM-bound.
// hmm_scan: one wave per (batch-group of 16, chunk of 32 + 8 warmup).
//   Permuted-K A fragments make the packed MFMA D-output directly the next
//   step's B-fragment — alpha never leaves registers; no barrier in loop.
//   Telescoped normalization (B-table pre-scaled by 64): 2-3 shfl
//   reductions per chunk.

#define BATCH 128
#define TLEN 8192
#define NS 128
#define EMIT 64
#define NCHUNK 256
#define CLEN (TLEN / NCHUNK)   // 32
#define WARM 8
#define BG 8                   // batch groups of 16
#define BSTR 132               // B-table row stride (bf16 elems)
#define LN64 4.158883083359672f
#define DBLK 2048              // decode blocks

typedef __attribute__((ext_vector_type(8))) short short8;
typedef __attribute__((ext_vector_type(4))) float floatx4;
typedef __attribute__((ext_vector_type(4))) unsigned int uintx4;

__device__ __forceinline__ unsigned f2bf(float f) {
    return (__float_as_uint(f) + 0x8000u) >> 16;   // round-half-up to bf16
}

// decode 256 MiB one-hot -> obsG[bg][n][t] bytes (1 MiB); also zeroes out_ll
__global__ __launch_bounds__(256) void decode_onehot(
        const floatx4* __restrict__ x, unsigned char* __restrict__ obsG,
        float* __restrict__ out_ll) {
    if (blockIdx.x == 0 && threadIdx.x < BATCH) out_ll[threadIdx.x] = 0.f;
    const int total = BATCH * TLEN * 16;           // float4 count
    #pragma unroll 1
    for (int s = 0; s < total / (DBLK * 1024); ++s) {
        int i0 = (s * DBLK + blockIdx.x) * 1024 + threadIdx.x;
        // 4 independent loads issued before any consume
        floatx4 v0 = x[i0];
        floatx4 v1 = x[i0 + 256];
        floatx4 v2 = x[i0 + 512];
        floatx4 v3 = x[i0 + 768];
        #pragma unroll
        for (int k = 0; k < 4; ++k) {
            floatx4 v = (k == 0) ? v0 : (k == 1) ? v1 : (k == 2) ? v2 : v3;
            int i = i0 + k * 256;
            float sm = v.x + v.y + v.z + v.w;
            if (sm > 0.5f) {
                int e = (v.y > 0.5f) ? 1 : (v.z > 0.5f) ? 2 : (v.w > 0.5f) ? 3 : 0;
                int elem = (i << 2) + e;
                int row = elem >> 6;               // b*TLEN + t
                int col = elem & 63;               // emission symbol
                int b = row >> 13;
                int t = row & (TLEN - 1);
                obsG[(b >> 4) * (16 * TLEN) + (b & 15) * TLEN + t] = (unsigned char)col;
            }
        }
    }
}

__global__ __launch_bounds__(64) void hmm_scan(
        const float* __restrict__ Amat,
        const float* __restrict__ Bmat,
        const float* __restrict__ Ivec,
        const unsigned char* __restrict__ obsG,
        float* __restrict__ out_alpha,    // [BATCH][NS]
        float* __restrict__ out_ll)       // [BATCH]
{
    __shared__ unsigned short Bl[EMIT * BSTR];    // 16896 B: bf16(64*B)

    const int lane = threadIdx.x;
    const int n = lane & 15;              // batch within group (D col)
    const int q = lane >> 4;              // quad
    const int bg = blockIdx.x >> 8;       // / NCHUNK
    const int c = blockIdx.x & (NCHUNK - 1);
    const bool first = (c == 0);
    const bool lastc = (c == NCHUNK - 1);
    const int steps = first ? CLEN : (CLEN + WARM);
    const int t0 = first ? 0 : c * CLEN - WARM;

    // stage B scaled by 64 (exact pow2) as bf16, padded stride
    for (int i = lane; i < EMIT * NS; i += 64) {
        int e = i >> 7, col = i & (NS - 1);
        Bl[e * BSTR + col] = (unsigned short)f2bf(64.0f * Bmat[i]);
    }

    // this lane's obs bytes -> 10 dwords in registers (obsG row is batch n)
    const unsigned char* orow = obsG + bg * (16 * TLEN) + n * TLEN;
    unsigned ow[10];
    if (first) {                          // t0==0: 32 bytes, 16B aligned
        uintx4 a = *(const uintx4*)(orow);
        uintx4 b = *(const uintx4*)(orow + 16);
        ow[0] = a.x; ow[1] = a.y; ow[2] = a.z; ow[3] = a.w;
        ow[4] = b.x; ow[5] = b.y; ow[6] = b.z; ow[7] = b.w;
        ow[8] = 0; ow[9] = 0;
    } else {                              // t0 = 32c-8: 8B then 16B aligned
        uint2 a = *(const uint2*)(orow + t0);
        uintx4 b = *(const uintx4*)(orow + t0 + 8);
        uintx4 d = *(const uintx4*)(orow + t0 + 24);
        ow[0] = a.x; ow[1] = a.y;
        ow[2] = b.x; ow[3] = b.y; ow[4] = b.z; ow[5] = b.w;
        ow[6] = d.x; ow[7] = d.y; ow[8] = d.z; ow[9] = d.w;
    }

    // A fragments with permuted K-order so packed D == next B-frag.
    // position u = 32kf+8q+j -> state 32(u>>5)+16((u>>2)&1)+4((u>>3)&3)+(u&3)
    short8 af[8][4];
    #pragma unroll
    for (int mt = 0; mt < 8; ++mt)
        #pragma unroll
        for (int kf = 0; kf < 4; ++kf) {
            short8 v;
            #pragma unroll
            for (int j = 0; j < 8; ++j) {
                int u = 32 * kf + 8 * q + j;
                int sk = 32 * (u >> 5) + 16 * ((u >> 2) & 1)
                       + 4 * ((u >> 3) & 3) + (u & 3);
                v[j] = (short)f2bf(Amat[sk * NS + 16 * mt + n]);
            }
            af[mt][kf] = v;
        }
    __syncthreads();   // Bl ready

    // loop-carried packed alpha (bf16 pairs); init uniform for warmup
    unsigned pk[16];
    #pragma unroll
    for (int i = 0; i < 16; ++i) pk[i] = 0x3C003C00u;   // bf16(1/128) x2

    float s_pre = 1.0f, s_penult = 1.0f, s_end = 1.0f;

    for (int it = 0; it < steps; ++it) {
        floatx4 acc[8];
        if (first && it == 0) {
            // t==0: R := I (exact init), alpha0 = 64B[o] * I
            #pragma unroll
            for (int mt = 0; mt < 8; ++mt)
                acc[mt] = *(const floatx4*)(Ivec + 16 * mt + 4 * q);
        } else {
            short8 bf[4];
            #pragma unroll
            for (int kf = 0; kf < 4; ++kf) {
                uintx4 u4 = {pk[4 * kf], pk[4 * kf + 1], pk[4 * kf + 2], pk[4 * kf + 3]};
                bf[kf] = __builtin_bit_cast(short8, u4);
            }
            #pragma unroll
            for (int mt = 0; mt < 8; ++mt) {
                floatx4 a = {0.f, 0.f, 0.f, 0.f};
                #pragma unroll
                for (int kf = 0; kf < 4; ++kf)
                    a = __builtin_amdgcn_mfma_f32_16x16x32_bf16(af[mt][kf], bf[kf], a, 0, 0, 0);
                acc[mt] = a;
            }
        }

        // emission multiply (table holds 64*B)
        int o = (ow[it >> 2] >> ((it & 3) * 8)) & 0xFF;
        int eb = o * BSTR;
        #pragma unroll
        for (int mt = 0; mt < 8; ++mt) {
            const unsigned* ep = (const unsigned*)(Bl + eb + 16 * mt + 4 * q);
            unsigned d0 = ep[0], d1 = ep[1];
            acc[mt].x *= __uint_as_float(d0 << 16);
            acc[mt].y *= __uint_as_float(d0 & 0xFFFF0000u);
            acc[mt].z *= __uint_as_float(d1 << 16);
            acc[mt].w *= __uint_as_float(d1 & 0xFFFF0000u);
        }

        // rare per-chunk reductions (wave-uniform branch)
        bool need_red = (it == steps - 1) || (!first && it == WARM - 1) ||
                        (lastc && it == steps - 2);
        if (need_red) {
            float zz = 0.f;
            #pragma unroll
            for (int mt = 0; mt < 8; ++mt)
                zz += (acc[mt].x + acc[mt].y) + (acc[mt].z + acc[mt].w);
            zz += __shfl_xor(zz, 16, 64);
            zz += __shfl_xor(zz, 32, 64);      // S-bar per batch, all q-lanes
            if (it == steps - 1) s_end = zz;
            else if (lastc && it == steps - 2) s_penult = zz;
            else s_pre = zz;
        }

        if (lastc && it == steps - 1) {
            // alpha_f = alpha-bar_{T-1} / (64 * S-bar_{T-2})
            float inv = 1.0f / (64.0f * s_penult);
            #pragma unroll
            for (int mt = 0; mt < 8; ++mt) {
                floatx4 o4;
                o4.x = acc[mt].x * inv; o4.y = acc[mt].y * inv;
                o4.z = acc[mt].z * inv; o4.w = acc[mt].w * inv;
                *(floatx4*)(out_alpha + (bg * 16 + n) * NS + 16 * mt + 4 * q) = o4;
            }
        }

        // pack to bf16 pairs: directly forms next step's B-fragments
        #pragma unroll
        for (int mt = 0; mt < 8; ++mt) {
            unsigned u0 = __float_as_uint(acc[mt].x) + 0x8000u;
            unsigned u1 = __float_as_uint(acc[mt].y) + 0x8000u;
            unsigned u2 = __float_as_uint(acc[mt].z) + 0x8000u;
            unsigned u3 = __float_as_uint(acc[mt].w) + 0x8000u;
            pk[2 * mt]     = __builtin_amdgcn_perm(u1, u0, 0x07060302u);
            pk[2 * mt + 1] = __builtin_amdgcn_perm(u3, u2, 0x07060302u);
        }
    }

    // chunk ll partial: telescoped  log(S_end) - log(S_pre) - CLEN*ln(64)
    if (q == 0) {
        float ll = __logf(s_end) - __logf(s_pre) - (float)CLEN * LN64;
        atomicAdd(&out_ll[bg * 16 + n], ll);
    }
}

extern "C" void kernel_launch(void* const* d_in, const int* in_sizes, int n_in,
                              void* d_out, int out_size, void* d_ws, size_t ws_size,
                              hipStream_t stream) {
    const float* x = (const float*)d_in[0];   // [B, T, EMIT] one-hot fp32
    const float* I = (const float*)d_in[1];   // [NS]
    const float* A = (const float*)d_in[2];   // [NS, NS]
    const float* B = (const float*)d_in[3];   // [EMIT, NS]
    float* out = (float*)d_out;               // alpha_f [B*NS] ++ loglik [B]

    unsigned char* obsG = (unsigned char*)d_ws;   // [BG][16][TLEN] bytes = 1 MiB

    decode_onehot<<<DBLK, 256, 0, stream>>>(
        (const floatx4*)x, obsG, out + BATCH * NS);
    hmm_scan<<<BG * NCHUNK, 64, 0, stream>>>(A, B, I, obsG, out, out + BATCH * NS);
}